// Round 1
// baseline (2209.915 us; speedup 1.0000x reference)
//
#include <hip/hip_runtime.h>
#include <hip/hip_bf16.h>
#include <cfloat>
#include <cstddef>

// ---------------------------------------------------------------------------
// Fused CNN kernel: conv3x3(SAME)+BN+ReLU+maxpool2 -> conv3x3(SAME)+BN+ReLU
// -> avgpool(4x4)->5x5, one block (256 thr) per node. fp32.
// LDS: padded input [CIN][42][42] (reused as conv2 output [C2][20][20]),
//      padded pooled [C1][20][22], folded BN scale/bias.
// ---------------------------------------------------------------------------
template <int CIN, int C1, int C2>
__global__ __launch_bounds__(256) void cnn_kernel(
    const float* __restrict__ img,
    const float* __restrict__ w1, const float* __restrict__ b1,
    const float* __restrict__ g1, const float* __restrict__ be1,
    const float* __restrict__ m1, const float* __restrict__ v1,
    const float* __restrict__ w2, const float* __restrict__ b2,
    const float* __restrict__ g2, const float* __restrict__ be2,
    const float* __restrict__ m2, const float* __restrict__ v2,
    float* __restrict__ xout, int featBase)
{
    extern __shared__ float smem[];
    constexpr int IN_F = CIN * 42 * 42;
    constexpr int C2OUT = C2 * 400;
    constexpr int R0 = (IN_F > C2OUT) ? IN_F : C2OUT;
    constexpr int POOL_F = C1 * 20 * 22;
    constexpr int TOT = R0 + POOL_F + 2 * C1 + 2 * C2;

    float* in_s   = smem;              // also conv2 output
    float* pool_s = smem + R0;
    float* sc1 = pool_s + POOL_F;
    float* bi1 = sc1 + C1;
    float* sc2 = bi1 + C1;
    float* bi2 = sc2 + C2;

    const int tid = threadIdx.x;
    const int n = blockIdx.x;

    for (int i = tid; i < TOT; i += 256) smem[i] = 0.0f;
    __syncthreads();

    // ---- load image into padded LDS (zero border from memset above)
    const float* ip = img + (size_t)n * (CIN * 1600);
    for (int p = tid * 4; p < CIN * 1600; p += 1024) {
        const float4 v = *(const float4*)(ip + p);
        int ci = p / 1600, rem = p % 1600;
        int y = rem / 40, x = rem % 40;
        float* d = in_s + ci * 1764 + (y + 1) * 42 + (x + 1);
        d[0] = v.x; d[1] = v.y; d[2] = v.z; d[3] = v.w;
    }
    // ---- fold BN (+conv bias): y = conv*sc + bi
    if (tid < C1) {
        float inv = g1[tid] / sqrtf(v1[tid] + 1e-5f);
        sc1[tid] = inv;
        bi1[tid] = b1[tid] * inv + be1[tid] - m1[tid] * inv;
    } else if (tid >= 64 && tid < 64 + C2) {
        int c = tid - 64;
        float inv = g2[c] / sqrtf(v2[c] + 1e-5f);
        sc2[c] = inv;
        bi2[c] = b2[c] * inv + be2[c] - m2[c] * inv;
    }
    __syncthreads();

    // ---- conv1 + BN + ReLU + 2x2 maxpool -> pool_s[c][py][px+1]
    for (int t = tid; t < 400; t += 256) {
        int py = t / 20, px = t % 20;
        float win[CIN][4][4];
#pragma unroll
        for (int ci = 0; ci < CIN; ++ci)
#pragma unroll
            for (int r = 0; r < 4; ++r) {
                const float* p = in_s + ci * 1764 + (2 * py + r) * 42 + 2 * px;
                win[ci][r][0] = p[0]; win[ci][r][1] = p[1];
                win[ci][r][2] = p[2]; win[ci][r][3] = p[3];
            }
        for (int c = 0; c < C1; ++c) {   // wave-uniform -> scalar weight loads
            const float* w = w1 + c * (CIN * 9);
            float a00 = 0.f, a01 = 0.f, a10 = 0.f, a11 = 0.f;
#pragma unroll
            for (int ci = 0; ci < CIN; ++ci)
#pragma unroll
                for (int ky = 0; ky < 3; ++ky)
#pragma unroll
                    for (int kx = 0; kx < 3; ++kx) {
                        float wv = w[ci * 9 + ky * 3 + kx];
                        a00 = fmaf(win[ci][ky][kx],         wv, a00);
                        a01 = fmaf(win[ci][ky][kx + 1],     wv, a01);
                        a10 = fmaf(win[ci][ky + 1][kx],     wv, a10);
                        a11 = fmaf(win[ci][ky + 1][kx + 1], wv, a11);
                    }
            float s = sc1[c], bb = bi1[c];
            float r00 = fmaxf(fmaf(a00, s, bb), 0.f);
            float r01 = fmaxf(fmaf(a01, s, bb), 0.f);
            float r10 = fmaxf(fmaf(a10, s, bb), 0.f);
            float r11 = fmaxf(fmaf(a11, s, bb), 0.f);
            pool_s[c * 440 + py * 22 + px + 1] =
                fmaxf(fmaxf(r00, r01), fmaxf(r10, r11));
        }
    }
    __syncthreads();

    // ---- conv2 + BN + ReLU -> in_s reused as [C2][20][20]
    for (int t = tid; t < 400; t += 256) {
        int y = t / 20, x = t % 20;
        float acc[C2];
#pragma unroll
        for (int c = 0; c < C2; ++c) acc[c] = 0.f;
        for (int ci = 0; ci < C1; ++ci) {   // uniform
            float v[3][3];
#pragma unroll
            for (int ky = 0; ky < 3; ++ky) {
                int r = y + ky - 1;
                bool ok = (r >= 0) && (r < 20);
                const float* p = pool_s + ci * 440 + (ok ? r : 0) * 22 + x;
                v[ky][0] = ok ? p[0] : 0.f;
                v[ky][1] = ok ? p[1] : 0.f;
                v[ky][2] = ok ? p[2] : 0.f;
            }
            const float* w = w2 + ci * 9;
#pragma unroll
            for (int c = 0; c < C2; ++c) {
                const float* wc = w + c * (C1 * 9);
#pragma unroll
                for (int ky = 0; ky < 3; ++ky)
#pragma unroll
                    for (int kx = 0; kx < 3; ++kx)
                        acc[c] = fmaf(v[ky][kx], wc[ky * 3 + kx], acc[c]);
            }
        }
#pragma unroll
        for (int c = 0; c < C2; ++c)
            in_s[c * 400 + t] = fmaxf(fmaf(acc[c], sc2[c], bi2[c]), 0.f);
    }
    __syncthreads();

    // ---- 4x4 avgpool -> x[n][featBase + c*25 + py*5 + px]
    float* xrow = xout + (size_t)n * 616 + featBase;
    for (int t = tid; t < C2 * 25; t += 256) {
        int c = t / 25, rr = t % 25;
        int py = rr / 5, px = rr % 5;
        const float* p = in_s + c * 400 + (4 * py) * 20 + 4 * px;
        float s = 0.f;
#pragma unroll
        for (int i = 0; i < 4; ++i)
#pragma unroll
            for (int j = 0; j < 4; ++j) s += p[i * 20 + j];
        xrow[t] = s * (1.0f / 16.0f);
    }
}

constexpr int cnn_smem_floats(int CIN, int C1, int C2) {
    int inf = CIN * 42 * 42;
    int r0 = (inf > C2 * 400) ? inf : C2 * 400;
    return r0 + C1 * 20 * 22 + 2 * C1 + 2 * C2;
}

// ---------------------------------------------------------------------------
__global__ void embed_kernel(const int* __restrict__ irr,
                             const float* __restrict__ emb,
                             float* __restrict__ x, int N)
{
    int t = blockIdx.x * 256 + threadIdx.x;
    if (t < N * 16) {
        int n = t >> 4, j = t & 15;
        x[(size_t)n * 616 + 600 + j] = emb[irr[n] * 16 + j];
    }
}

__global__ void deg_kernel(const int* __restrict__ dst, int* __restrict__ deg, int E)
{
    int e = blockIdx.x * 256 + threadIdx.x;
    if (e < E) atomicAdd(&deg[dst[e]], 1);
}

// single-block exclusive scan over deg[0..n) -> row_start (n+1), cursor (copy)
__global__ __launch_bounds__(256) void scan_kernel(const int* __restrict__ deg,
                                                   int* __restrict__ row_start,
                                                   int* __restrict__ cursor, int n)
{
    __shared__ int buf[256];
    int t = threadIdx.x;
    int chunk = (n + 255) >> 8;
    int base = t * chunk;
    int s = 0;
    for (int j = 0; j < chunk; ++j) {
        int idx = base + j;
        if (idx < n) s += deg[idx];
    }
    buf[t] = s;
    __syncthreads();
    for (int off = 1; off < 256; off <<= 1) {
        int u = (t >= off) ? buf[t - off] : 0;
        __syncthreads();
        buf[t] += u;
        __syncthreads();
    }
    int run = buf[t] - s;   // exclusive prefix
    for (int j = 0; j < chunk; ++j) {
        int idx = base + j;
        if (idx < n) {
            row_start[idx] = run;
            cursor[idx] = run;
            run += deg[idx];
        }
    }
    if (t == 255) row_start[n] = run;
}

__global__ void scatter_kernel(const int* __restrict__ src, const int* __restrict__ dst,
                               int* __restrict__ cursor, int* __restrict__ csr, int E)
{
    int e = blockIdx.x * 256 + threadIdx.x;
    if (e < E) {
        int p = atomicAdd(&cursor[dst[e]], 1);
        csr[p] = src[e];
    }
}

// ---------------------------------------------------------------------------
// agg1: per-node segment-max over 616-dim rows; one wave per node.
// ---------------------------------------------------------------------------
__global__ __launch_bounds__(256) void agg1_kernel(
    const float* __restrict__ x, const int* __restrict__ row_start,
    const int* __restrict__ csr, float* __restrict__ agg, int N)
{
    int w = threadIdx.x >> 6, lane = threadIdx.x & 63;
    int i = blockIdx.x * 4 + w;
    if (i >= N) return;
    int rs = row_start[i], re = row_start[i + 1];
    for (int c = 0; c < 10; ++c) {
        int d = c * 64 + lane;
        bool act = d < 616;
        float m = -FLT_MAX;
        for (int e = rs; e < re; ++e) {
            int s = csr[e];   // uniform -> scalar load
            if (act) m = fmaxf(m, x[(size_t)s * 616 + d]);
        }
        if (act) agg[(size_t)i * 616 + d] = (re > rs) ? m : 0.0f;
    }
}

// ---------------------------------------------------------------------------
// SAGE1: x1 = relu(agg@wl^T + x@wr^T + bl).  Tiled fp32 GEMM, 64 nodes x 64
// outs per block, 256 threads as 16x16, 4x4 acc each, K-tiles of 16.
// ---------------------------------------------------------------------------
__global__ __launch_bounds__(256) void sage1_gemm(
    const float* __restrict__ agg, const float* __restrict__ xf,
    const float* __restrict__ wl, const float* __restrict__ wr,
    const float* __restrict__ bl, float* __restrict__ x1, int N)
{
    __shared__ float As[16 * 68];
    __shared__ float Bs[16 * 68];
    const int t = threadIdx.x;
    const int tx = t & 15, ty = t >> 4;
    const int nodeBase = blockIdx.x * 64;
    const int lr = t >> 2;          // 0..63 row (node / out) for staging
    const int lk4 = (t & 3) * 4;    // k sub-offset

    float acc[4][4];
#pragma unroll
    for (int i = 0; i < 4; ++i)
#pragma unroll
        for (int j = 0; j < 4; ++j) acc[i][j] = 0.f;

    for (int phase = 0; phase < 2; ++phase) {
        const float* A = phase ? xf : agg;
        const float* W = phase ? wr : wl;
        for (int k0 = 0; k0 < 616; k0 += 16) {
            // stage A^T: As[k][node]
            float a0 = 0.f, a1 = 0.f, a2 = 0.f, a3 = 0.f;
            int node = nodeBase + lr;
            if (node < N) {
                if (k0 + lk4 + 3 < 616) {
                    const float4 v = *(const float4*)&A[(size_t)node * 616 + k0 + lk4];
                    a0 = v.x; a1 = v.y; a2 = v.z; a3 = v.w;
                } else {
                    const float* p = &A[(size_t)node * 616];
                    if (k0 + lk4 + 0 < 616) a0 = p[k0 + lk4 + 0];
                    if (k0 + lk4 + 1 < 616) a1 = p[k0 + lk4 + 1];
                    if (k0 + lk4 + 2 < 616) a2 = p[k0 + lk4 + 2];
                    if (k0 + lk4 + 3 < 616) a3 = p[k0 + lk4 + 3];
                }
            }
            As[(lk4 + 0) * 68 + lr] = a0;
            As[(lk4 + 1) * 68 + lr] = a1;
            As[(lk4 + 2) * 68 + lr] = a2;
            As[(lk4 + 3) * 68 + lr] = a3;
            // stage B^T: Bs[k][o]
            float b0 = 0.f, b1 = 0.f, b2 = 0.f, b3 = 0.f;
            {
                if (k0 + lk4 + 3 < 616) {
                    const float4 v = *(const float4*)&W[(size_t)lr * 616 + k0 + lk4];
                    b0 = v.x; b1 = v.y; b2 = v.z; b3 = v.w;
                } else {
                    const float* p = &W[(size_t)lr * 616];
                    if (k0 + lk4 + 0 < 616) b0 = p[k0 + lk4 + 0];
                    if (k0 + lk4 + 1 < 616) b1 = p[k0 + lk4 + 1];
                    if (k0 + lk4 + 2 < 616) b2 = p[k0 + lk4 + 2];
                    if (k0 + lk4 + 3 < 616) b3 = p[k0 + lk4 + 3];
                }
            }
            Bs[(lk4 + 0) * 68 + lr] = b0;
            Bs[(lk4 + 1) * 68 + lr] = b1;
            Bs[(lk4 + 2) * 68 + lr] = b2;
            Bs[(lk4 + 3) * 68 + lr] = b3;
            __syncthreads();
#pragma unroll
            for (int kk = 0; kk < 16; ++kk) {
                const float4 a = *(const float4*)&As[kk * 68 + 4 * ty];
                const float4 b = *(const float4*)&Bs[kk * 68 + 4 * tx];
                float ar[4] = {a.x, a.y, a.z, a.w};
                float br[4] = {b.x, b.y, b.z, b.w};
#pragma unroll
                for (int i = 0; i < 4; ++i)
#pragma unroll
                    for (int j = 0; j < 4; ++j)
                        acc[i][j] = fmaf(ar[i], br[j], acc[i][j]);
            }
            __syncthreads();
        }
    }
    // epilogue: + bl, relu, store
#pragma unroll
    for (int i = 0; i < 4; ++i) {
        int node = nodeBase + 4 * ty + i;
        if (node < N) {
            float4 o;
            o.x = fmaxf(acc[i][0] + bl[4 * tx + 0], 0.f);
            o.y = fmaxf(acc[i][1] + bl[4 * tx + 1], 0.f);
            o.z = fmaxf(acc[i][2] + bl[4 * tx + 2], 0.f);
            o.w = fmaxf(acc[i][3] + bl[4 * tx + 3], 0.f);
            *(float4*)&x1[(size_t)node * 64 + 4 * tx] = o;
        }
    }
}

// ---------------------------------------------------------------------------
// SAGE2 + FC fused: agg2 (max over x1 rows), x2 = relu(agg2@wl^T + x1@wr^T +
// bl), out = x2@fc^T + fcb.  One wave per node, 4 nodes per block.
// ---------------------------------------------------------------------------
__global__ __launch_bounds__(256) void sage2_kernel(
    const float* __restrict__ x1, const int* __restrict__ row_start,
    const int* __restrict__ csr,
    const float* __restrict__ wl, const float* __restrict__ bl,
    const float* __restrict__ wr,
    const float* __restrict__ fcw, const float* __restrict__ fcb,
    float* __restrict__ out, int N)
{
    __shared__ float wlS[32 * 65];
    __shared__ float wrS[32 * 65];
    __shared__ float aS[4][64];
    __shared__ float xiS[4][64];
    const int tid = threadIdx.x;
    for (int i = tid; i < 2048; i += 256) {
        wlS[(i >> 6) * 65 + (i & 63)] = wl[i];
        wrS[(i >> 6) * 65 + (i & 63)] = wr[i];
    }
    __syncthreads();
    const int w = tid >> 6, lane = tid & 63;
    const int i = blockIdx.x * 4 + w;
    const bool act = i < N;
    float a = 0.f, xi = 0.f;
    if (act) {
        int rs = row_start[i], re = row_start[i + 1];
        float m = -FLT_MAX;
        for (int e = rs; e < re; ++e) {
            int s = csr[e];
            m = fmaxf(m, x1[(size_t)s * 64 + lane]);
        }
        a = (re > rs) ? m : 0.f;
        xi = x1[(size_t)i * 64 + lane];
    }
    aS[w][lane] = a;
    xiS[w][lane] = xi;
    __syncthreads();
    float y = 0.f;
    if (act && lane < 32) {
        float acc = bl[lane];
#pragma unroll
        for (int d = 0; d < 64; ++d)
            acc = fmaf(aS[w][d], wlS[lane * 65 + d],
                       fmaf(xiS[w][d], wrS[lane * 65 + d], acc));
        y = fmaxf(acc, 0.f) * fcw[lane];
    }
    y += __shfl_down(y, 32);
    y += __shfl_down(y, 16);
    y += __shfl_down(y, 8);
    y += __shfl_down(y, 4);
    y += __shfl_down(y, 2);
    y += __shfl_down(y, 1);
    if (act && lane == 0) out[i] = y + fcb[0];
}

// ---------------------------------------------------------------------------
extern "C" void kernel_launch(void* const* d_in, const int* in_sizes, int n_in,
                              void* d_out, int out_size, void* d_ws, size_t ws_size,
                              hipStream_t stream)
{
    const float* veg  = (const float*)d_in[0];
    const float* cwsi = (const float*)d_in[1];
    const int*   irr  = (const int*)d_in[2];
    const int*   edges = (const int*)d_in[3];
    const float* veg_w1 = (const float*)d_in[4];
    const float* veg_b1 = (const float*)d_in[5];
    const float* veg_g1 = (const float*)d_in[6];
    const float* veg_be1 = (const float*)d_in[7];
    const float* veg_m1 = (const float*)d_in[8];
    const float* veg_v1 = (const float*)d_in[9];
    const float* veg_w2 = (const float*)d_in[10];
    const float* veg_b2 = (const float*)d_in[11];
    const float* veg_g2 = (const float*)d_in[12];
    const float* veg_be2 = (const float*)d_in[13];
    const float* veg_m2 = (const float*)d_in[14];
    const float* veg_v2 = (const float*)d_in[15];
    const float* cwsi_w1 = (const float*)d_in[16];
    const float* cwsi_b1 = (const float*)d_in[17];
    const float* cwsi_g1 = (const float*)d_in[18];
    const float* cwsi_be1 = (const float*)d_in[19];
    const float* cwsi_m1 = (const float*)d_in[20];
    const float* cwsi_v1 = (const float*)d_in[21];
    const float* cwsi_w2 = (const float*)d_in[22];
    const float* cwsi_b2 = (const float*)d_in[23];
    const float* cwsi_g2 = (const float*)d_in[24];
    const float* cwsi_be2 = (const float*)d_in[25];
    const float* cwsi_m2 = (const float*)d_in[26];
    const float* cwsi_v2 = (const float*)d_in[27];
    const float* emb = (const float*)d_in[28];
    const float* s1_wl = (const float*)d_in[29];
    const float* s1_bl = (const float*)d_in[30];
    const float* s1_wr = (const float*)d_in[31];
    const float* s2_wl = (const float*)d_in[32];
    const float* s2_bl = (const float*)d_in[33];
    const float* s2_wr = (const float*)d_in[34];
    const float* fc_w = (const float*)d_in[35];
    const float* fc_b = (const float*)d_in[36];

    const int N = in_sizes[2];
    const int E = in_sizes[3] / 2;
    const int* src = edges;
    const int* dst = edges + E;

    // workspace carve-up
    char* wsb = (char*)d_ws;
    size_t off = 0;
    auto alloc = [&](size_t bytes) -> void* {
        void* p = wsb + off;
        off = (off + bytes + 255) & ~(size_t)255;
        return p;
    };
    float* xf  = (float*)alloc((size_t)N * 616 * sizeof(float));
    float* agg = (float*)alloc((size_t)N * 616 * sizeof(float));
    float* x1  = (float*)alloc((size_t)N * 64 * sizeof(float));
    int* deg       = (int*)alloc((size_t)N * sizeof(int));
    int* row_start = (int*)alloc((size_t)(N + 1) * sizeof(int));
    int* cursor    = (int*)alloc((size_t)N * sizeof(int));
    int* csr       = (int*)alloc((size_t)E * sizeof(int));
    (void)ws_size; (void)n_in; (void)out_size;

    hipMemsetAsync(deg, 0, (size_t)N * sizeof(int), stream);

    const size_t smem_veg  = cnn_smem_floats(5, 16, 16) * sizeof(float);  // 63696 B
    const size_t smem_cwsi = cnn_smem_floats(1, 16, 8) * sizeof(float);   // 41152 B

    cnn_kernel<5, 16, 16><<<N, 256, smem_veg, stream>>>(
        veg, veg_w1, veg_b1, veg_g1, veg_be1, veg_m1, veg_v1,
        veg_w2, veg_b2, veg_g2, veg_be2, veg_m2, veg_v2, xf, 0);
    cnn_kernel<1, 16, 8><<<N, 256, smem_cwsi, stream>>>(
        cwsi, cwsi_w1, cwsi_b1, cwsi_g1, cwsi_be1, cwsi_m1, cwsi_v1,
        cwsi_w2, cwsi_b2, cwsi_g2, cwsi_be2, cwsi_m2, cwsi_v2, xf, 400);
    embed_kernel<<<(N * 16 + 255) / 256, 256, 0, stream>>>(irr, emb, xf, N);

    deg_kernel<<<(E + 255) / 256, 256, 0, stream>>>(dst, deg, E);
    scan_kernel<<<1, 256, 0, stream>>>(deg, row_start, cursor, N);
    scatter_kernel<<<(E + 255) / 256, 256, 0, stream>>>(src, dst, cursor, csr, E);

    agg1_kernel<<<(N + 3) / 4, 256, 0, stream>>>(xf, row_start, csr, agg, N);
    sage1_gemm<<<(N + 63) / 64, 256, 0, stream>>>(agg, xf, s1_wl, s1_wr, s1_bl, x1, N);
    sage2_kernel<<<(N + 3) / 4, 256, 0, stream>>>(
        x1, row_start, csr, s2_wl, s2_bl, s2_wr, fc_w, fc_b, (float*)d_out, N);
}

// Round 2
// 1218.266 us; speedup vs baseline: 1.8140x; 1.8140x over previous
//
#include <hip/hip_runtime.h>
#include <hip/hip_bf16.h>
#include <cfloat>
#include <cstddef>

using bf16x8  = __attribute__((ext_vector_type(8))) short;
using floatx4 = __attribute__((ext_vector_type(4))) float;

union ABfrag { bf16x8 f; unsigned u[4]; short s[8]; };

__device__ __forceinline__ unsigned short f2bf(float x) {
    unsigned u = __float_as_uint(x);
    u += 0x7FFFu + ((u >> 16) & 1u);
    return (unsigned short)(u >> 16);
}
__device__ __forceinline__ float bf2f(unsigned short h) {
    return __uint_as_float((unsigned)h << 16);
}
// pack hi|lo bf16 decomposition of x into one u32: low 16 = hi, high 16 = lo
__device__ __forceinline__ unsigned pack_hilo(float x) {
    unsigned short hi = f2bf(x);
    unsigned short lo = f2bf(x - bf2f(hi));
    return ((unsigned)lo << 16) | (unsigned)hi;
}

// ---------------------------------------------------------------------------
// MFMA CNN: conv3x3+BN+ReLU+maxpool2 -> conv3x3+BN+ReLU -> avgpool4 -> 5x5.
// One node per 256-thread block (4 waves). 16x16x32 bf16 MFMA.
// conv1: A = input (hi/lo split, 3-term), K-mapping k=(ci*3+ky)*4+kx (kx=3 dummy)
// conv2: A = pooled acts (single bf16, ch-last LDS), B = weights hi/lo (2-term),
//        K-mapping k=(ky*3+kx)*16+ci  -> one aligned ds_read_b128 per frag.
// ---------------------------------------------------------------------------
template <int CIN, int C1, int C2>
__global__ __launch_bounds__(256, 3) void cnn_mfma_kernel(
    const float* __restrict__ img,
    const float* __restrict__ w1, const float* __restrict__ b1,
    const float* __restrict__ g1, const float* __restrict__ be1,
    const float* __restrict__ m1, const float* __restrict__ v1,
    const float* __restrict__ w2, const float* __restrict__ b2,
    const float* __restrict__ g2, const float* __restrict__ be2,
    const float* __restrict__ m2, const float* __restrict__ v2,
    float* __restrict__ xout, int featBase)
{
    static_assert(C1 == 16, "conv1 out channels must be 16");
    constexpr int KC1 = CIN * 3;                 // (ci,ky) chunk count
    constexpr int NK1 = (KC1 * 4 + 31) / 32;     // mfma count conv1 (veg 2, cwsi 1)
    constexpr int NK2 = (C1 * 9 + 31) / 32;      // = 5 (K=144 -> 160)
    constexpr int IN_U32 = CIN * 42 * 43;        // packed hi|lo input, padded
    constexpr int IN_AL  = (IN_U32 + 3) & ~3;    // align pool base to 16B
    constexpr int POOL_U16 = 22 * 23 * 16;       // ch-last pooled acts, padded

    extern __shared__ unsigned smem_u32[];
    unsigned* in_s = smem_u32;
    unsigned short* pool16 = (unsigned short*)(smem_u32 + IN_AL);
    float* sc1 = (float*)(pool16 + POOL_U16);
    float* bi1 = sc1 + C1;
    float* sc2 = bi1 + C1;
    float* bi2 = sc2 + C2;

    const int tid  = threadIdx.x;
    const int lane = tid & 63;
    const int wv   = tid >> 6;
    const int quad = lane >> 4;
    const int ch   = lane & 15;     // A-row m for staging; D-col (channel) for output
    const int n    = blockIdx.x;

    // ---- zero LDS (input borders + pool borders)
    for (int i = tid; i < IN_AL + POOL_U16 / 2; i += 256) smem_u32[i] = 0u;

    // ---- B-fragment preload (global only, no LDS dependence)
    ABfrag b1hi[NK1], b1lo[NK1], b2hi[NK2], b2lo[NK2];
#pragma unroll
    for (int mi = 0; mi < NK1; ++mi)
#pragma unroll
        for (int j = 0; j < 8; ++j) {
            int k = mi * 32 + quad * 8 + j;
            int c = k >> 2, kx = k & 3;
            float wvv = 0.f;
            if (c < KC1 && kx < 3)
                wvv = w1[ch * (CIN * 9) + (c / 3) * 9 + (c % 3) * 3 + kx];
            unsigned short h = f2bf(wvv);
            b1hi[mi].s[j] = (short)h;
            b1lo[mi].s[j] = (short)f2bf(wvv - bf2f(h));
        }
#pragma unroll
    for (int mi = 0; mi < NK2; ++mi)
#pragma unroll
        for (int j = 0; j < 8; ++j) {
            int k = mi * 32 + quad * 8 + j;
            int g = k >> 4, ci = k & 15;
            float wvv = 0.f;
            if (g < 9 && ch < C2)
                wvv = w2[ch * (C1 * 9) + ci * 9 + (g / 3) * 3 + (g % 3)];
            unsigned short h = f2bf(wvv);
            b2hi[mi].s[j] = (short)h;
            b2lo[mi].s[j] = (short)f2bf(wvv - bf2f(h));
        }

    // ---- per-lane A-chunk offsets (invariant over tiles)
    int offA[NK1 * 2];
#pragma unroll
    for (int mi = 0; mi < NK1; ++mi)
#pragma unroll
        for (int h = 0; h < 2; ++h) {
            int c = mi * 8 + quad * 2 + h;
            offA[mi * 2 + h] = (c < KC1) ? (c / 3) * 1806 + (c % 3) * 43 : 0;
        }
    int off2[NK2];
#pragma unroll
    for (int mi = 0; mi < NK2; ++mi) {
        int g = (mi * 32 + quad * 8) >> 4;
        off2[mi] = (g < 9) ? ((g / 3) * 23 + (g % 3)) * 16 + (quad & 1) * 8 : 0;
    }

    __syncthreads();   // zero-fill complete

    // ---- stage input: fp32 -> packed hi|lo u32, padded [CIN][42][43]
    const float* ip = img + (size_t)n * (CIN * 1600);
    for (int p = tid * 4; p < CIN * 1600; p += 1024) {
        const float4 v = *(const float4*)(ip + p);
        int ci = p / 1600, rem = p % 1600;
        int y = rem / 40, x = rem % 40;
        unsigned* d = in_s + ci * 1806 + (y + 1) * 43 + (x + 1);
        d[0] = pack_hilo(v.x); d[1] = pack_hilo(v.y);
        d[2] = pack_hilo(v.z); d[3] = pack_hilo(v.w);
    }
    // ---- folded BN params
    if (tid < C1) {
        float inv = g1[tid] / sqrtf(v1[tid] + 1e-5f);
        sc1[tid] = inv;
        bi1[tid] = b1[tid] * inv + be1[tid] - m1[tid] * inv;
    } else if (tid >= 32 && tid < 32 + C2) {
        int c = tid - 32;
        float inv = g2[c] / sqrtf(v2[c] + 1e-5f);
        sc2[c] = inv;
        bi2[c] = b2[c] * inv + be2[c] - m2[c] * inv;
    }
    __syncthreads();

    // ---- conv1 + BN + ReLU + maxpool2: 100 tiles of 2x8 conv pixels
    {
        const int r  = ch >> 3;        // row within tile (A-role: m = lane&15)
        const int cc = ch & 7;         // col within tile
        for (int t = wv; t < 100; t += 4) {
            int ty = t / 5, tx = t % 5;
            int base = (2 * ty + r) * 43 + 8 * tx + cc;
            floatx4 acc = {0.f, 0.f, 0.f, 0.f};
#pragma unroll
            for (int mi = 0; mi < NK1; ++mi) {
                ABfrag hi, lo;
#pragma unroll
                for (int h = 0; h < 2; ++h) {
                    int a = offA[mi * 2 + h] + base;
                    unsigned p0 = in_s[a], p1 = in_s[a + 1], p2 = in_s[a + 2];
                    hi.u[2 * h]     = (p0 & 0xffffu) | (p1 << 16);
                    hi.u[2 * h + 1] = (p2 & 0xffffu) | (p2 << 16);
                    lo.u[2 * h]     = (p0 >> 16) | (p1 & 0xffff0000u);
                    lo.u[2 * h + 1] = (p2 >> 16) | (p2 & 0xffff0000u);
                }
                acc = __builtin_amdgcn_mfma_f32_16x16x32_bf16(hi.f, b1hi[mi].f, acc, 0, 0, 0);
                acc = __builtin_amdgcn_mfma_f32_16x16x32_bf16(hi.f, b1lo[mi].f, acc, 0, 0, 0);
                acc = __builtin_amdgcn_mfma_f32_16x16x32_bf16(lo.f, b1hi[mi].f, acc, 0, 0, 0);
            }
            // epilogue: D col = ch (channel), rows = 4*quad + reg = pixel-in-tile
            float s = sc1[ch], bb = bi1[ch];
            float v0 = fmaxf(fmaf(acc[0], s, bb), 0.f);
            float v1 = fmaxf(fmaf(acc[1], s, bb), 0.f);
            float v2 = fmaxf(fmaf(acc[2], s, bb), 0.f);
            float v3 = fmaxf(fmaf(acc[3], s, bb), 0.f);
            float pa = fmaxf(v0, v1), pb = fmaxf(v2, v3);
            pa = fmaxf(pa, __shfl_xor(pa, 32));
            pb = fmaxf(pb, __shfl_xor(pb, 32));
            if (lane < 32) {   // quads 0,1 hold the pooled results
                int pc = tx * 4 + 2 * quad;
                int idx = ((ty + 1) * 23 + pc + 1) * 16 + ch;
                pool16[idx]      = f2bf(pa);
                pool16[idx + 16] = f2bf(pb);
            }
        }
    }
    __syncthreads();

    // ---- conv2 + BN + ReLU + avgpool4: 25 tiles = 25 output cells (4x4 pixels)
    {
        const int dy = ch >> 2, dx = ch & 3;    // A-role: m = lane&15 -> pixel in 4x4
        float* xrow = xout + (size_t)n * 616 + featBase;
        for (int t = wv; t < 25; t += 4) {
            int c5y = t / 5, c5x = t % 5;
            int base2 = ((4 * c5y + dy) * 23 + 4 * c5x + dx) * 16;
            floatx4 acc = {0.f, 0.f, 0.f, 0.f};
#pragma unroll
            for (int mi = 0; mi < NK2; ++mi) {
                bf16x8 a = *(const bf16x8*)(pool16 + base2 + off2[mi]);
                acc = __builtin_amdgcn_mfma_f32_16x16x32_bf16(a, b2hi[mi].f, acc, 0, 0, 0);
                acc = __builtin_amdgcn_mfma_f32_16x16x32_bf16(a, b2lo[mi].f, acc, 0, 0, 0);
            }
            int c2i = (ch < C2) ? ch : 0;
            float s = sc2[c2i], bb = bi2[c2i];
            float sum = fmaxf(fmaf(acc[0], s, bb), 0.f)
                      + fmaxf(fmaf(acc[1], s, bb), 0.f)
                      + fmaxf(fmaf(acc[2], s, bb), 0.f)
                      + fmaxf(fmaf(acc[3], s, bb), 0.f);
            sum += __shfl_xor(sum, 16);
            sum += __shfl_xor(sum, 32);
            if (quad == 0 && ch < C2)
                xrow[ch * 25 + t] = sum * (1.f / 16.f);
        }
    }
}

constexpr int cnn_mfma_smem(int CIN, int C1, int C2) {
    int in_al = (CIN * 42 * 43 + 3) & ~3;
    return in_al * 4 + 22 * 23 * 16 * 2 + (2 * C1 + 2 * C2) * 4;
}

// ---------------------------------------------------------------------------
__global__ void embed_kernel(const int* __restrict__ irr,
                             const float* __restrict__ emb,
                             float* __restrict__ x, int N)
{
    int t = blockIdx.x * 256 + threadIdx.x;
    if (t < N * 16) {
        int n = t >> 4, j = t & 15;
        x[(size_t)n * 616 + 600 + j] = emb[irr[n] * 16 + j];
    }
}

__global__ void deg_kernel(const int* __restrict__ dst, int* __restrict__ deg, int E)
{
    int e = blockIdx.x * 256 + threadIdx.x;
    if (e < E) atomicAdd(&deg[dst[e]], 1);
}

__global__ __launch_bounds__(256) void scan_kernel(const int* __restrict__ deg,
                                                   int* __restrict__ row_start,
                                                   int* __restrict__ cursor, int n)
{
    __shared__ int buf[256];
    int t = threadIdx.x;
    int chunk = (n + 255) >> 8;
    int base = t * chunk;
    int s = 0;
    for (int j = 0; j < chunk; ++j) {
        int idx = base + j;
        if (idx < n) s += deg[idx];
    }
    buf[t] = s;
    __syncthreads();
    for (int off = 1; off < 256; off <<= 1) {
        int u = (t >= off) ? buf[t - off] : 0;
        __syncthreads();
        buf[t] += u;
        __syncthreads();
    }
    int run = buf[t] - s;
    for (int j = 0; j < chunk; ++j) {
        int idx = base + j;
        if (idx < n) {
            row_start[idx] = run;
            cursor[idx] = run;
            run += deg[idx];
        }
    }
    if (t == 255) row_start[n] = run;
}

__global__ void scatter_kernel(const int* __restrict__ src, const int* __restrict__ dst,
                               int* __restrict__ cursor, int* __restrict__ csr, int E)
{
    int e = blockIdx.x * 256 + threadIdx.x;
    if (e < E) {
        int p = atomicAdd(&cursor[dst[e]], 1);
        csr[p] = src[e];
    }
}

// ---------------------------------------------------------------------------
// agg1: segment-max over 616-dim rows; one wave per node, float4 loads.
// ---------------------------------------------------------------------------
__global__ __launch_bounds__(256) void agg1_kernel(
    const float* __restrict__ x, const int* __restrict__ row_start,
    const int* __restrict__ csr, float* __restrict__ agg, int N)
{
    int w = threadIdx.x >> 6, lane = threadIdx.x & 63;
    int i = blockIdx.x * 4 + w;
    if (i >= N) return;
    int rs = row_start[i], re = row_start[i + 1];
    const bool a2 = lane < 26;   // 512 + 4*lane < 616
    float4 m0 = {-FLT_MAX, -FLT_MAX, -FLT_MAX, -FLT_MAX};
    float4 m1 = m0, m2 = m0;
    for (int e = rs; e < re; ++e) {
        int s = csr[e];
        const float* row = x + (size_t)s * 616;
        float4 v0 = *(const float4*)(row + 4 * lane);
        float4 v1 = *(const float4*)(row + 256 + 4 * lane);
        m0.x = fmaxf(m0.x, v0.x); m0.y = fmaxf(m0.y, v0.y);
        m0.z = fmaxf(m0.z, v0.z); m0.w = fmaxf(m0.w, v0.w);
        m1.x = fmaxf(m1.x, v1.x); m1.y = fmaxf(m1.y, v1.y);
        m1.z = fmaxf(m1.z, v1.z); m1.w = fmaxf(m1.w, v1.w);
        if (a2) {
            float4 v2 = *(const float4*)(row + 512 + 4 * lane);
            m2.x = fmaxf(m2.x, v2.x); m2.y = fmaxf(m2.y, v2.y);
            m2.z = fmaxf(m2.z, v2.z); m2.w = fmaxf(m2.w, v2.w);
        }
    }
    if (re <= rs) { float4 z = {0.f, 0.f, 0.f, 0.f}; m0 = z; m1 = z; m2 = z; }
    float* out = agg + (size_t)i * 616;
    *(float4*)(out + 4 * lane) = m0;
    *(float4*)(out + 256 + 4 * lane) = m1;
    if (a2) *(float4*)(out + 512 + 4 * lane) = m2;
}

// ---------------------------------------------------------------------------
// SAGE1: x1 = relu(agg@wl^T + x@wr^T + bl). 64x64 tile fp32 GEMM.
// ---------------------------------------------------------------------------
__global__ __launch_bounds__(256) void sage1_gemm(
    const float* __restrict__ agg, const float* __restrict__ xf,
    const float* __restrict__ wl, const float* __restrict__ wr,
    const float* __restrict__ bl, float* __restrict__ x1, int N)
{
    __shared__ float As[16 * 68];
    __shared__ float Bs[16 * 68];
    const int t = threadIdx.x;
    const int tx = t & 15, ty = t >> 4;
    const int nodeBase = blockIdx.x * 64;
    const int lr = t >> 2;
    const int lk4 = (t & 3) * 4;

    float acc[4][4];
#pragma unroll
    for (int i = 0; i < 4; ++i)
#pragma unroll
        for (int j = 0; j < 4; ++j) acc[i][j] = 0.f;

    for (int phase = 0; phase < 2; ++phase) {
        const float* A = phase ? xf : agg;
        const float* W = phase ? wr : wl;
        for (int k0 = 0; k0 < 616; k0 += 16) {
            float a0 = 0.f, a1 = 0.f, a2 = 0.f, a3 = 0.f;
            int node = nodeBase + lr;
            if (node < N) {
                if (k0 + lk4 + 3 < 616) {
                    const float4 v = *(const float4*)&A[(size_t)node * 616 + k0 + lk4];
                    a0 = v.x; a1 = v.y; a2 = v.z; a3 = v.w;
                } else {
                    const float* p = &A[(size_t)node * 616];
                    if (k0 + lk4 + 0 < 616) a0 = p[k0 + lk4 + 0];
                    if (k0 + lk4 + 1 < 616) a1 = p[k0 + lk4 + 1];
                    if (k0 + lk4 + 2 < 616) a2 = p[k0 + lk4 + 2];
                    if (k0 + lk4 + 3 < 616) a3 = p[k0 + lk4 + 3];
                }
            }
            As[(lk4 + 0) * 68 + lr] = a0;
            As[(lk4 + 1) * 68 + lr] = a1;
            As[(lk4 + 2) * 68 + lr] = a2;
            As[(lk4 + 3) * 68 + lr] = a3;
            float b0 = 0.f, b1 = 0.f, b2 = 0.f, b3 = 0.f;
            {
                if (k0 + lk4 + 3 < 616) {
                    const float4 v = *(const float4*)&W[(size_t)lr * 616 + k0 + lk4];
                    b0 = v.x; b1 = v.y; b2 = v.z; b3 = v.w;
                } else {
                    const float* p = &W[(size_t)lr * 616];
                    if (k0 + lk4 + 0 < 616) b0 = p[k0 + lk4 + 0];
                    if (k0 + lk4 + 1 < 616) b1 = p[k0 + lk4 + 1];
                    if (k0 + lk4 + 2 < 616) b2 = p[k0 + lk4 + 2];
                }
            }
            Bs[(lk4 + 0) * 68 + lr] = b0;
            Bs[(lk4 + 1) * 68 + lr] = b1;
            Bs[(lk4 + 2) * 68 + lr] = b2;
            Bs[(lk4 + 3) * 68 + lr] = b3;
            __syncthreads();
#pragma unroll
            for (int kk = 0; kk < 16; ++kk) {
                const float4 a = *(const float4*)&As[kk * 68 + 4 * ty];
                const float4 b = *(const float4*)&Bs[kk * 68 + 4 * tx];
                float ar[4] = {a.x, a.y, a.z, a.w};
                float br[4] = {b.x, b.y, b.z, b.w};
#pragma unroll
                for (int i = 0; i < 4; ++i)
#pragma unroll
                    for (int j = 0; j < 4; ++j)
                        acc[i][j] = fmaf(ar[i], br[j], acc[i][j]);
            }
            __syncthreads();
        }
    }
#pragma unroll
    for (int i = 0; i < 4; ++i) {
        int node = nodeBase + 4 * ty + i;
        if (node < N) {
            float4 o;
            o.x = fmaxf(acc[i][0] + bl[4 * tx + 0], 0.f);
            o.y = fmaxf(acc[i][1] + bl[4 * tx + 1], 0.f);
            o.z = fmaxf(acc[i][2] + bl[4 * tx + 2], 0.f);
            o.w = fmaxf(acc[i][3] + bl[4 * tx + 3], 0.f);
            *(float4*)&x1[(size_t)node * 64 + 4 * tx] = o;
        }
    }
}

// ---------------------------------------------------------------------------
// SAGE2 + FC fused.
// ---------------------------------------------------------------------------
__global__ __launch_bounds__(256) void sage2_kernel(
    const float* __restrict__ x1, const int* __restrict__ row_start,
    const int* __restrict__ csr,
    const float* __restrict__ wl, const float* __restrict__ bl,
    const float* __restrict__ wr,
    const float* __restrict__ fcw, const float* __restrict__ fcb,
    float* __restrict__ out, int N)
{
    __shared__ float wlS[32 * 65];
    __shared__ float wrS[32 * 65];
    __shared__ float aS[4][64];
    __shared__ float xiS[4][64];
    const int tid = threadIdx.x;
    for (int i = tid; i < 2048; i += 256) {
        wlS[(i >> 6) * 65 + (i & 63)] = wl[i];
        wrS[(i >> 6) * 65 + (i & 63)] = wr[i];
    }
    __syncthreads();
    const int w = tid >> 6, lane = tid & 63;
    const int i = blockIdx.x * 4 + w;
    const bool act = i < N;
    float a = 0.f, xi = 0.f;
    if (act) {
        int rs = row_start[i], re = row_start[i + 1];
        float m = -FLT_MAX;
        for (int e = rs; e < re; ++e) {
            int s = csr[e];
            m = fmaxf(m, x1[(size_t)s * 64 + lane]);
        }
        a = (re > rs) ? m : 0.f;
        xi = x1[(size_t)i * 64 + lane];
    }
    aS[w][lane] = a;
    xiS[w][lane] = xi;
    __syncthreads();
    float y = 0.f;
    if (act && lane < 32) {
        float acc = bl[lane];
#pragma unroll
        for (int d = 0; d < 64; ++d)
            acc = fmaf(aS[w][d], wlS[lane * 65 + d],
                       fmaf(xiS[w][d], wrS[lane * 65 + d], acc));
        y = fmaxf(acc, 0.f) * fcw[lane];
    }
    y += __shfl_down(y, 32);
    y += __shfl_down(y, 16);
    y += __shfl_down(y, 8);
    y += __shfl_down(y, 4);
    y += __shfl_down(y, 2);
    y += __shfl_down(y, 1);
    if (act && lane == 0) out[i] = y + fcb[0];
}

// ---------------------------------------------------------------------------
extern "C" void kernel_launch(void* const* d_in, const int* in_sizes, int n_in,
                              void* d_out, int out_size, void* d_ws, size_t ws_size,
                              hipStream_t stream)
{
    const float* veg  = (const float*)d_in[0];
    const float* cwsi = (const float*)d_in[1];
    const int*   irr  = (const int*)d_in[2];
    const int*   edges = (const int*)d_in[3];
    const float* veg_w1 = (const float*)d_in[4];
    const float* veg_b1 = (const float*)d_in[5];
    const float* veg_g1 = (const float*)d_in[6];
    const float* veg_be1 = (const float*)d_in[7];
    const float* veg_m1 = (const float*)d_in[8];
    const float* veg_v1 = (const float*)d_in[9];
    const float* veg_w2 = (const float*)d_in[10];
    const float* veg_b2 = (const float*)d_in[11];
    const float* veg_g2 = (const float*)d_in[12];
    const float* veg_be2 = (const float*)d_in[13];
    const float* veg_m2 = (const float*)d_in[14];
    const float* veg_v2 = (const float*)d_in[15];
    const float* cwsi_w1 = (const float*)d_in[16];
    const float* cwsi_b1 = (const float*)d_in[17];
    const float* cwsi_g1 = (const float*)d_in[18];
    const float* cwsi_be1 = (const float*)d_in[19];
    const float* cwsi_m1 = (const float*)d_in[20];
    const float* cwsi_v1 = (const float*)d_in[21];
    const float* cwsi_w2 = (const float*)d_in[22];
    const float* cwsi_b2 = (const float*)d_in[23];
    const float* cwsi_g2 = (const float*)d_in[24];
    const float* cwsi_be2 = (const float*)d_in[25];
    const float* cwsi_m2 = (const float*)d_in[26];
    const float* cwsi_v2 = (const float*)d_in[27];
    const float* emb = (const float*)d_in[28];
    const float* s1_wl = (const float*)d_in[29];
    const float* s1_bl = (const float*)d_in[30];
    const float* s1_wr = (const float*)d_in[31];
    const float* s2_wl = (const float*)d_in[32];
    const float* s2_bl = (const float*)d_in[33];
    const float* s2_wr = (const float*)d_in[34];
    const float* fc_w = (const float*)d_in[35];
    const float* fc_b = (const float*)d_in[36];

    const int N = in_sizes[2];
    const int E = in_sizes[3] / 2;
    const int* src = edges;
    const int* dst = edges + E;

    char* wsb = (char*)d_ws;
    size_t off = 0;
    auto alloc = [&](size_t bytes) -> void* {
        void* p = wsb + off;
        off = (off + bytes + 255) & ~(size_t)255;
        return p;
    };
    float* xf  = (float*)alloc((size_t)N * 616 * sizeof(float));
    float* agg = (float*)alloc((size_t)N * 616 * sizeof(float));
    float* x1  = (float*)alloc((size_t)N * 64 * sizeof(float));
    int* deg       = (int*)alloc((size_t)N * sizeof(int));
    int* row_start = (int*)alloc((size_t)(N + 1) * sizeof(int));
    int* cursor    = (int*)alloc((size_t)N * sizeof(int));
    int* csr       = (int*)alloc((size_t)E * sizeof(int));
    (void)ws_size; (void)n_in; (void)out_size;

    hipMemsetAsync(deg, 0, (size_t)N * sizeof(int), stream);

    const size_t smem_veg  = cnn_mfma_smem(5, 16, 16);   // 52,576 B -> 3 blocks/CU
    const size_t smem_cwsi = cnn_mfma_smem(1, 16, 8);    // 23,616 B

    cnn_mfma_kernel<5, 16, 16><<<N, 256, smem_veg, stream>>>(
        veg, veg_w1, veg_b1, veg_g1, veg_be1, veg_m1, veg_v1,
        veg_w2, veg_b2, veg_g2, veg_be2, veg_m2, veg_v2, xf, 0);
    cnn_mfma_kernel<1, 16, 8><<<N, 256, smem_cwsi, stream>>>(
        cwsi, cwsi_w1, cwsi_b1, cwsi_g1, cwsi_be1, cwsi_m1, cwsi_v1,
        cwsi_w2, cwsi_b2, cwsi_g2, cwsi_be2, cwsi_m2, cwsi_v2, xf, 400);
    embed_kernel<<<(N * 16 + 255) / 256, 256, 0, stream>>>(irr, emb, xf, N);

    deg_kernel<<<(E + 255) / 256, 256, 0, stream>>>(dst, deg, E);
    scan_kernel<<<1, 256, 0, stream>>>(deg, row_start, cursor, N);
    scatter_kernel<<<(E + 255) / 256, 256, 0, stream>>>(src, dst, cursor, csr, E);

    agg1_kernel<<<(N + 3) / 4, 256, 0, stream>>>(xf, row_start, csr, agg, N);
    sage1_gemm<<<(N + 63) / 64, 256, 0, stream>>>(agg, xf, s1_wl, s1_wr, s1_bl, x1, N);
    sage2_kernel<<<(N + 3) / 4, 256, 0, stream>>>(
        x1, row_start, csr, s2_wl, s2_bl, s2_wr, fc_w, fc_b, (float*)d_out, N);
}